// Round 20
// baseline (258.995 us; speedup 1.0000x reference)
//
#include <hip/hip_runtime.h>
#include <stdint.h>

// MeanConv: out = mask * (1/7) * sum_{k in 3,5,..,15} boxmean_k(x), edge padding.
// Per-tile 2D integral image in LDS; box sum = 4-corner difference.
// Base = measured-best r2 form (PSTR 83, 16px/thread span-merged P3, scalar
// P-writes): 78.7us. All LDS-cost variants (word count, b128 width) measured
// neutral; occupancy up/down neutral/worse; reg-prefetch pipeline lost 42%
// to VGPR (48->112). Remaining consistent theory: PHASE CONVOY — HBM burst
// (P1) and LDS burst (P3) are barrier-separated and ADD (~27us + ~34us+...)
// instead of overlapping; no pipe >42% busy.
// THIS ROUND: TLP-neutral overlap via global_load_lds (zero VGPR):
//   2 vertical tiles per block; tile-1's x rows are DMA'd into XS (25.6KB
//   LDS) by __builtin_amdgcn_global_load_lds issued before tile-0's P3.
//   The barrier after P3 drains vmcnt; tile-1's P1 reads XS (ds_read_b128)
//   instead of global. Edge blocks (x-clamp breaks 16B runs) use the old
//   global path. LDS 26.9+25.6=52.5KB -> 3 blocks/CU = 12 waves (= r2's 11).
// Falsifier from r10: VGPR must stay <=64.

#define TILE   64
#define HALO   7
#define LHX    8            // left halo (8 for float4 alignment)
#define NCOL   80           // staged cols: c0-8 .. c0+71
#define NROW   78           // staged rows: r0-7 .. r0+70
#define PSTR   83           // odd; 2-way-free bank patterns (measured best)
#define PROWSA 81           // rows 0..78 used + 2 slack
#define HH     4096
#define WW     4096
#define XSTR   80           // XS row stride (floats); rows 16B-aligned
#define XCHUNK 25           // 25 chunks x 1024B = 80 rows x 80 floats

__global__ __launch_bounds__(256) void meanconv_kernel(
    const float* __restrict__ x, const float* __restrict__ mask,
    float* __restrict__ out)
{
    __shared__ float P[PROWSA * PSTR];   // 26892 B
    __shared__ float XS[XCHUNK * 256];   // 25600 B (rows 78,79 = DMA pad)
    const int tid    = threadIdx.x;
    const int c0     = blockIdx.x * TILE;
    const int r0base = blockIdx.y * (2 * TILE);

    // zero row 0 (cols 0..80); never rewritten, stays zero for both tiles
    if (tid < 81) P[tid] = 0.0f;

    const bool xint = (c0 >= LHX) && (c0 - LHX + NCOL <= WW);

    // P1: stage (from global or XS) + row prefix + 4-lane shfl fixup.
    auto p1_pass = [&](int r0, int mode) {   // mode: 0=global, 1=XS
        for (int idx = tid; idx < NROW * 4; idx += 256) {
            const int lr = idx >> 2;         // staged row 0..77
            const int s  = idx & 3;          // 20-col segment
            float v[20];
            if (mode == 1) {
                const float* sr = &XS[lr * XSTR + 20 * s];
                #pragma unroll
                for (int q = 0; q < 5; ++q) {
                    const float4 t4 = *(const float4*)(sr + 4 * q);
                    v[4*q+0] = t4.x; v[4*q+1] = t4.y;
                    v[4*q+2] = t4.z; v[4*q+3] = t4.w;
                }
            } else {
                const int gr  = min(max(r0 + lr - HALO, 0), HH - 1);
                const int gc0 = c0 - LHX + 20 * s;
                if (xint) {
                    const float* src = &x[(size_t)gr * WW + gc0];
                    #pragma unroll
                    for (int q = 0; q < 5; ++q) {
                        const float4 t4 = *(const float4*)(src + 4 * q);
                        v[4*q+0] = t4.x; v[4*q+1] = t4.y;
                        v[4*q+2] = t4.z; v[4*q+3] = t4.w;
                    }
                } else {
                    #pragma unroll
                    for (int i = 0; i < 20; ++i) {
                        const int gc = min(max(gc0 + i, 0), WW - 1);
                        v[i] = x[(size_t)gr * WW + gc];
                    }
                }
            }
            #pragma unroll
            for (int i = 1; i < 20; ++i) v[i] += v[i - 1];
            const float tot = v[19];
            float sum = tot;
            float u = __shfl_up(sum, 1, 4); if (s >= 1) sum += u;
            u       = __shfl_up(sum, 2, 4); if (s >= 2) sum += u;
            const float off = sum - tot;
            float* dst = &P[(lr + 1) * PSTR + 1 + 20 * s];
            #pragma unroll
            for (int i = 0; i < 20; ++i) dst[i] = v[i] + off;
        }
    };

    // P3 thread mapping: col group g (16 px), tile row ty
    const int g  = tid & 3;
    const int ty = tid >> 2;             // 0..63
    const int B0 = 16 * g;
    const int A  = ty + HALO;

    for (int t = 0; t < 2; ++t) {
        const int r0 = r0base + TILE * t;

        // ---- phase 1 ----
        if (t == 0)      p1_pass(r0, 0);
        else if (xint)   p1_pass(r0, 1);
        else             p1_pass(r0, 0);
        __syncthreads();

        // ---- phase 2: column prefix over rows 1..78 ----
        for (int idx = tid; idx < 80 * 4; idx += 256) {
            const int c  = (idx >> 2) + 1;   // col 1..80
            const int s  = idx & 3;
            const int rs = 1 + 20 * s;
            float vv[20];
            float run = 0.0f;
            #pragma unroll
            for (int i = 0; i < 20; ++i) {
                const int r = rs + i;
                float tt = P[r * PSTR + c];  // rows 79,80 in-bounds slack
                tt = (r < 79) ? tt : 0.0f;
                run += tt; vv[i] = run;
            }
            const float tot = run;
            float sum = tot;
            float u = __shfl_up(sum, 1, 4); if (s >= 1) sum += u;
            u       = __shfl_up(sum, 2, 4); if (s >= 2) sum += u;
            const float off = sum - tot;
            #pragma unroll
            for (int i = 0; i < 20; ++i) {
                const int r = rs + i;
                if (r < 79) P[r * PSTR + c] = vv[i] + off;
            }
        }
        __syncthreads();
        // P[a][b] = sum of staged[row < a][col < b].

        // ---- async DMA: stage tile-1's x into XS (zero VGPR cost) ----
        // Issued before P3; the post-P3 barrier's vmcnt drain completes it.
        if (t == 0 && xint) {
            const int wv = tid >> 6, ln = tid & 63;
            const int r1 = r0base + TILE;
            for (int ch = wv; ch < XCHUNK; ch += 4) {
                const int u_  = ch * 64 + ln;      // 16B unit index
                const int row = u_ / 20;           // XS row 0..79
                const int c4  = u_ - row * 20;     // float4 within row
                const int gr  = min(max(r1 + row - HALO, 0), HH - 1);
                const float* src = &x[(size_t)gr * WW + (c0 - LHX + 4 * c4)];
                float* dst = &XS[ch * 256];        // wave-uniform base
                __builtin_amdgcn_global_load_lds(
                    (const uint32_t*)src, (uint32_t*)dst, 16, 0, 0);
            }
        }

        // ---- phase 3: 16 px/thread, span-merged corner reads ----
        float a[16];
        #pragma unroll
        for (int i = 0; i < 16; ++i) a[i] = 0.0f;
        #pragma unroll
        for (int p = 1; p <= 7; ++p) {
            const int   k   = 2 * p + 1;
            const float wgt = 1.0f / (7.0f * (float)(k * k));
            const int   W   = 17 + 2 * p;    // span cols [B0+8-p, B0+24+p]
            const float* rT = &P[(A - p)     * PSTR + B0 + LHX - p];
            const float* rB = &P[(A + p + 1) * PSTR + B0 + LHX - p];
            float D[31];
            #pragma unroll
            for (int q = 0; q < W; ++q) D[q] = rB[q] - rT[q];
            #pragma unroll
            for (int i = 0; i < 16; ++i)
                a[i] += wgt * (D[k + i] - D[i]);
        }
        if (t == 0) __syncthreads();   // protect P for t=1's P1; drains DMA

        const int gr = r0 + ty, gc = c0 + B0;
        const float* mrow = &mask[(size_t)gr * WW + gc];
        float*       orow = &out[(size_t)gr * WW + gc];
        #pragma unroll
        for (int q = 0; q < 4; ++q) {
            const float4 m = *(const float4*)(mrow + 4 * q);
            float4 o4;
            o4.x = a[4*q+0] * m.x;
            o4.y = a[4*q+1] * m.y;
            o4.z = a[4*q+2] * m.z;
            o4.w = a[4*q+3] * m.w;
            *(float4*)(orow + 4 * q) = o4;
        }
    }
}

extern "C" void kernel_launch(void* const* d_in, const int* in_sizes, int n_in,
                              void* d_out, int out_size, void* d_ws, size_t ws_size,
                              hipStream_t stream) {
    const float* x    = (const float*)d_in[0];
    const float* mask = (const float*)d_in[1];
    float*       out  = (float*)d_out;
    dim3 grid(WW / TILE, HH / (2 * TILE));
    meanconv_kernel<<<grid, 256, 0, stream>>>(x, mask, out);
}